// Round 1
// 798.093 us; speedup vs baseline: 1.1185x; 1.1185x over previous
//
#include <hip/hip_runtime.h>
#include <hip/hip_bf16.h>

// DeepSeekMoE on MI355X. FP32 inputs/output per reference; bf16 MFMA compute.
// Sparse top-2 dispatch (exact vs dense reference: non-topk gates are 0).
// Gate layer-1 uses split-bf16 3-term GEMM so top-2 selection matches fp32 ref.
// R6: attack the 2-barrier drain (m233: stage+vmcnt+barrier ~72% of critical
// path in this structure):
//  (1) SPLIT fused into ONE K-loop: co-stage xb/xl/gw1h/gw1l 128x32 subtiles,
//      48 MFMA per barrier pair (was 3 passes x 16) -> 3x fewer drains, 1.5x
//      less staging traffic on the gate GEMM (the top dispatch, 183us).
//  (2) BK 32->64 for dense/gather GEMMs (LDS 32KB, 32 MFMA per barrier pair).
//  (3) Full-rank XOR swizzle: BK=64 rows = 8x16B slots, slot = c ^ (row&7)
//      -> every quarter-wave hits all 8 bank quadrants 2x (2-way = free);
//      BK=32 split path adds the (row>>2)&1 bit for the same uniform spread.
//      Linear LDS dest + inverse-swizzled GLOBAL source + swizzled read.

using bf16 = __hip_bfloat16;
typedef __attribute__((ext_vector_type(8))) short short8;
typedef __attribute__((ext_vector_type(4))) float float4v;

#define T_TOK 8192
#define DDIM  1024
#define HDIM  2048
#define NEXP  8

__device__ __forceinline__ float bf2f(short s) {
  unsigned u = ((unsigned)(unsigned short)s) << 16;
  return __builtin_bit_cast(float, u);
}
__device__ __forceinline__ unsigned short f2bf(float f) {
  unsigned u = __builtin_bit_cast(unsigned, f);
  unsigned r = (u + 0x7fffu + ((u >> 16) & 1u)) >> 16;   // RNE
  return (unsigned short)r;
}
__device__ __forceinline__ float gelu_erf_f(float x) {
  return 0.5f * x * (1.0f + erff(x * 0.70710678118654752f));
}
__device__ __forceinline__ float gelu_tanh_f(float x) {
  float t = tanhf(0.7978845608028654f * (x + 0.044715f * x * x * x));
  return 0.5f * x * (1.0f + t);
}
__device__ __forceinline__ void gld_lds16(const bf16* g, bf16* l) {
  __builtin_amdgcn_global_load_lds(
      (const __attribute__((address_space(1))) void*)g,
      (__attribute__((address_space(3))) void*)l, 16, 0, 0);
}

// ---------------- cast x fp32 -> bf16 hi + bf16 residual ----------------
__global__ __launch_bounds__(256) void cast_split_x(
    const float* __restrict__ x, bf16* __restrict__ xh, bf16* __restrict__ xl)
{
  long i = ((long)blockIdx.x * 256 + threadIdx.x) * 4;
  float4v v = *(const float4v*)(x + i);
  short4 h, l;
  short* hp = (short*)&h; short* lp = (short*)&l;
  #pragma unroll
  for (int j = 0; j < 4; ++j) {
    unsigned short hb = f2bf(v[j]);
    hp[j] = (short)hb;
    lp[j] = (short)f2bf(v[j] - bf2f((short)hb));
  }
  *(short4*)((short*)xh + i) = h;
  *(short4*)((short*)xl + i) = l;
}

// ------------- transpose+cast fp32 [R,C] -> bf16 [C,R], batched z -------------
template<bool SPLIT>
__global__ __launch_bounds__(256) void transpose_cast(
    const float* __restrict__ in, bf16* __restrict__ out,
    bf16* __restrict__ outl, int R, int C)
{
  __shared__ float tile[32][33];
  long b = blockIdx.z;
  const float* ip = in + b * (long)R * C;
  short* op = (short*)out + b * (long)R * C;
  short* opl = SPLIT ? (short*)outl + b * (long)R * C : nullptr;
  int c0 = blockIdx.x * 32, r0 = blockIdx.y * 32;
  int tx = threadIdx.x & 31, ty = threadIdx.x >> 5;
  #pragma unroll
  for (int i = ty; i < 32; i += 8)
    tile[i][tx] = ip[(long)(r0 + i) * C + c0 + tx];
  __syncthreads();
  #pragma unroll
  for (int i = ty; i < 32; i += 8) {
    float v = tile[tx][i];
    unsigned short hb = f2bf(v);
    op[(long)(c0 + i) * R + r0 + tx] = (short)hb;
    if (SPLIT)
      opl[(long)(c0 + i) * R + r0 + tx] = (short)f2bf(v - bf2f((short)hb));
  }
}

// ---------------- tiled MFMA GEMM: C = act(A @ B^T + bias) ----------------
// A [M,Kd] bf16 (ldA), Bt [N,Kd] bf16 (+z*strideB), bias fp32 [N] (+z*strideBias).
// GATHER: 0 dense; 1 A-row = perm[i]>>1 (token); 2 A-row = perm[i] (slot).
// Gathered: C row = perm[i], M_eff = counts[z], early-exit tiles.
// ACT: 0 none, 1 gelu(erf), 2 gelu(tanh). WEIGHTED: scale by wslot[slot].
// SPLIT: single K-loop accumulating A@Bt + A@Btl + Al@Bt (dense only),
//        four co-staged 128x32 subtiles, 48 MFMA per barrier pair.
// COMBINE (dense fp32 out, N=DDIM): v += Rout[2*row] + Rout[2*row+1].
// LDS XOR-swizzle (both paths): 16B chunk (row,c) lives at slot
//   dense (BK=64): row*8 + (c ^ (row&7))
//   split (BK=32): row*4 + (c ^ (row&3) ^ ((row>>2)&1))
// staged via inverse-swizzled per-lane GLOBAL source (LDS dest stays linear).
template<int ACT, typename OutT, int GATHER, bool WEIGHTED, bool SPLIT, bool COMBINE>
__global__ __launch_bounds__(256) void gemm_bt(
    const bf16* __restrict__ A, const bf16* __restrict__ Bt,
    const bf16* __restrict__ Al, const bf16* __restrict__ Btl,
    const float* __restrict__ bias, OutT* __restrict__ Cmat,
    int M, int N, int Kd, int ldA,
    long strideB, long strideBias,
    const int* __restrict__ perm, const int* __restrict__ counts,
    const float* __restrict__ wslot, const bf16* __restrict__ RoutC)
{
  __shared__ __align__(16) bf16 lA[128 * 64];   // dense: A-tile 128x64
  __shared__ __align__(16) bf16 lB[128 * 64];   // split: [0:4096)=hi, [4096:8192)=lo
  __shared__ int permT[128];

  const int tid = threadIdx.x;
  const int tile_n = blockIdx.x, tile_m = blockIdx.y, z = blockIdx.z;

  int Meff = M;
  if (GATHER) {
    const int* perm_z = perm + (long)z * T_TOK;
    Meff = counts[z];
    if (tile_m * 128 >= Meff) return;   // uniform early-exit (before barriers)
    if (tid < 128) {
      int i = tile_m * 128 + tid;
      permT[tid] = perm_z[i < Meff ? i : (Meff - 1)];
    }
    __syncthreads();
  }
  const float* biasz = bias + (long)z * strideBias;

  const int lane = tid & 63;
  const int wave = tid >> 6;
  const int wm = (wave & 1) * 64;
  const int wn = (wave >> 1) * 64;
  const int fr = lane & 15;          // m/n index within 16x16 tile

  float4v acc[4][4];
  #pragma unroll
  for (int i = 0; i < 4; ++i)
    #pragma unroll
    for (int j = 0; j < 4; ++j) acc[i][j] = {0.f, 0.f, 0.f, 0.f};

  if constexpr (SPLIT) {
    // ---- gate GEMM: BK=32, four 128x32 subtiles, dense only ----
    const int i0 = tid >> 2;                    // row-in-tile (0..63)
    // staged chunk: row = i*64+i0, logical c = (tid&3)^(row&3)^((row>>2)&1)
    const int cS = (((tid & 3) ^ ((tid >> 2) & 3) ^ ((tid >> 4) & 1))) * 8;
    const long rA0 = (long)tile_m * 128 + i0;
    const long rA1 = rA0 + 64;
    const long rB0 = (long)tile_n * 128 + i0;

    const bf16* pAh0 = A   + rA0 * ldA + cS;
    const bf16* pAh1 = A   + rA1 * ldA + cS;
    const bf16* pAl0 = Al  + rA0 * ldA + cS;
    const bf16* pAl1 = Al  + rA1 * ldA + cS;
    const bf16* pBh0 = Bt  + rB0 * Kd + cS;
    const bf16* pBh1 = pBh0 + (long)64 * Kd;
    const bf16* pBl0 = Btl + rB0 * Kd + cS;
    const bf16* pBl1 = pBl0 + (long)64 * Kd;

    bf16* dAh0 = &lA[tid * 8];         bf16* dAh1 = &lA[(tid + 256) * 8];
    bf16* dAl0 = &lA[4096 + tid * 8];  bf16* dAl1 = &lA[4096 + (tid + 256) * 8];
    bf16* dBh0 = &lB[tid * 8];         bf16* dBh1 = &lB[(tid + 256) * 8];
    bf16* dBl0 = &lB[4096 + tid * 8];  bf16* dBl1 = &lB[4096 + (tid + 256) * 8];

    // fragment read: row=wm+mi*16+fr, logical c=lane>>4
    const int sw = (((lane >> 4) ^ (lane & 3) ^ ((lane >> 2) & 1))) * 8;

    for (int k0 = 0; k0 < Kd; k0 += 32) {
      gld_lds16(pAh0 + k0, dAh0); gld_lds16(pAh1 + k0, dAh1);
      gld_lds16(pAl0 + k0, dAl0); gld_lds16(pAl1 + k0, dAl1);
      gld_lds16(pBh0 + k0, dBh0); gld_lds16(pBh1 + k0, dBh1);
      gld_lds16(pBl0 + k0, dBl0); gld_lds16(pBl1 + k0, dBl1);
      __syncthreads();               // drains vmcnt -> LDS tiles visible

      short8 ah[4], alr[4], bh[4], blr[4];
      #pragma unroll
      for (int mi = 0; mi < 4; ++mi) {
        ah[mi]  = *(const short8*)&lA[(wm + mi * 16 + fr) * 32 + sw];
        alr[mi] = *(const short8*)&lA[4096 + (wm + mi * 16 + fr) * 32 + sw];
      }
      #pragma unroll
      for (int ni = 0; ni < 4; ++ni) {
        bh[ni]  = *(const short8*)&lB[(wn + ni * 16 + fr) * 32 + sw];
        blr[ni] = *(const short8*)&lB[4096 + (wn + ni * 16 + fr) * 32 + sw];
      }
      #pragma unroll
      for (int mi = 0; mi < 4; ++mi)
        #pragma unroll
        for (int ni = 0; ni < 4; ++ni)
          acc[mi][ni] = __builtin_amdgcn_mfma_f32_16x16x32_bf16(
              ah[mi], bh[ni], acc[mi][ni], 0, 0, 0);
      #pragma unroll
      for (int mi = 0; mi < 4; ++mi)
        #pragma unroll
        for (int ni = 0; ni < 4; ++ni)
          acc[mi][ni] = __builtin_amdgcn_mfma_f32_16x16x32_bf16(
              ah[mi], blr[ni], acc[mi][ni], 0, 0, 0);
      #pragma unroll
      for (int mi = 0; mi < 4; ++mi)
        #pragma unroll
        for (int ni = 0; ni < 4; ++ni)
          acc[mi][ni] = __builtin_amdgcn_mfma_f32_16x16x32_bf16(
              alr[mi], bh[ni], acc[mi][ni], 0, 0, 0);
      __syncthreads();               // all readers done before next staging
    }
  } else {
    // ---- dense / gathered: BK=64 ----
    const int r0 = tid >> 3;                    // 0..31
    // staged chunk: row = i*32+r0, logical c = (tid&7)^(row&7)  (i-invariant)
    const int cD = (((tid & 7) ^ ((tid >> 3) & 7))) * 8;

    const bf16* pA[4]; const bf16* pB[4]; bf16* dA[4]; bf16* dB[4];
    #pragma unroll
    for (int i = 0; i < 4; ++i) {
      int rt = i * 32 + r0;                     // row-in-tile 0..127
      long ra;
      if (GATHER) {
        int p = permT[rt];
        ra = (GATHER == 1) ? (long)(p >> 1) : (long)p;
      } else {
        ra = (long)tile_m * 128 + rt;
      }
      pA[i] = A + ra * ldA + cD;
      pB[i] = Bt + (long)z * strideB + ((long)tile_n * 128 + rt) * Kd + cD;
      dA[i] = &lA[(i * 256 + tid) * 8];
      dB[i] = &lB[(i * 256 + tid) * 8];
    }
    // fragment read: row=wm+mi*16+fr, logical c = kh*4 + (lane>>4)
    const int swb = (((lane >> 4) ^ (lane & 7))) * 8;

    for (int k0 = 0; k0 < Kd; k0 += 64) {
      #pragma unroll
      for (int i = 0; i < 4; ++i) gld_lds16(pA[i] + k0, dA[i]);
      #pragma unroll
      for (int i = 0; i < 4; ++i) gld_lds16(pB[i] + k0, dB[i]);
      __syncthreads();               // drains vmcnt -> LDS tile visible

      #pragma unroll
      for (int kh = 0; kh < 2; ++kh) {
        const int sw = swb ^ (kh * 32);         // (c^4)*8 == c*8 ^ 32
        short8 af[4], bfr[4];
        #pragma unroll
        for (int mi = 0; mi < 4; ++mi)
          af[mi] = *(const short8*)&lA[(wm + mi * 16 + fr) * 64 + sw];
        #pragma unroll
        for (int ni = 0; ni < 4; ++ni)
          bfr[ni] = *(const short8*)&lB[(wn + ni * 16 + fr) * 64 + sw];
        #pragma unroll
        for (int mi = 0; mi < 4; ++mi)
          #pragma unroll
          for (int ni = 0; ni < 4; ++ni)
            acc[mi][ni] = __builtin_amdgcn_mfma_f32_16x16x32_bf16(
                af[mi], bfr[ni], acc[mi][ni], 0, 0, 0);
      }
      __syncthreads();               // all readers done before next staging
    }
  }

  // --- epilogue: C/D layout col(n)=lane&15, row(m)=(lane>>4)*4+reg ---
  const int rq = ((lane >> 4)) * 4;
  #pragma unroll
  for (int mi = 0; mi < 4; ++mi) {
    #pragma unroll
    for (int r = 0; r < 4; ++r) {
      int irow = wm + mi * 16 + rq + r;
      int gi = tile_m * 128 + irow;
      long crow;
      bool valid = true;
      float w = 1.f;
      if (GATHER) {
        valid = gi < Meff;
        int p = permT[irow];
        crow = p;
        if (WEIGHTED) w = valid ? wslot[p] : 0.f;
      } else {
        crow = gi;
      }
      if (valid) {
        #pragma unroll
        for (int ni = 0; ni < 4; ++ni) {
          int gcol = tile_n * 128 + wn + ni * 16 + fr;
          float v = acc[mi][ni][r] + biasz[gcol];
          if (ACT == 1) v = gelu_erf_f(v);
          else if (ACT == 2) v = gelu_tanh_f(v);
          if (WEIGHTED) v *= w;
          if (COMBINE) {
            const short* rs = (const short*)RoutC;
            v += bf2f(rs[(2 * crow) * DDIM + gcol])
               + bf2f(rs[(2 * crow + 1) * DDIM + gcol]);
          }
          long cidx = crow * (long)N + gcol;
          if (sizeof(OutT) == 4) ((float*)Cmat)[cidx] = v;
          else ((unsigned short*)Cmat)[cidx] = f2bf(v);
        }
      }
    }
  }
}

// -------- logits: one wave per token; fp32 reduce; top-2 + softmax --------
__global__ __launch_bounds__(256) void logits_kernel(
    const float* __restrict__ G1, const float* __restrict__ gw2,
    const float* __restrict__ gb2, int* __restrict__ tidx,
    float* __restrict__ wslot)
{
  int wv = threadIdx.x >> 6, lane = threadIdx.x & 63;
  int t = blockIdx.x * 4 + wv;
  const float* grow = G1 + (long)t * HDIM;
  float acc[NEXP];
  #pragma unroll
  for (int e = 0; e < NEXP; ++e) acc[e] = 0.f;
  for (int j = 0; j < HDIM / 64; ++j) {
    int h = j * 64 + lane;
    float g = grow[h];                      // coalesced across the wave
    float4v w0 = *(const float4v*)&gw2[h * NEXP];
    float4v w1 = *(const float4v*)&gw2[h * NEXP + 4];
    #pragma unroll
    for (int e = 0; e < 4; ++e) {
      acc[e]     += g * w0[e];
      acc[e + 4] += g * w1[e];
    }
  }
  #pragma unroll
  for (int off = 32; off >= 1; off >>= 1)
    #pragma unroll
    for (int e = 0; e < NEXP; ++e) acc[e] += __shfl_xor(acc[e], off);

  if (lane == 0) {
    float lg[NEXP];
    #pragma unroll
    for (int e = 0; e < NEXP; ++e) lg[e] = acc[e] + gb2[e];
    int i1 = 0;
    for (int e = 1; e < NEXP; ++e) if (lg[e] > lg[i1]) i1 = e;   // ties -> lowest
    int i2 = (i1 == 0) ? 1 : 0;
    for (int e = 0; e < NEXP; ++e) {
      if (e == i1) continue;
      if (lg[e] > lg[i2]) i2 = e;
    }
    float m = lg[i1], s = 0.f;
    #pragma unroll
    for (int e = 0; e < NEXP; ++e) s += expf(lg[e] - m);
    float inv = 1.f / s;
    tidx[2 * t]     = i1;
    tidx[2 * t + 1] = i2;
    wslot[2 * t]     = expf(lg[i1] - m) * inv;
    wslot[2 * t + 1] = expf(lg[i2] - m) * inv;
  }
}

// -------- dispatch: ballot-aggregated per-expert slot lists --------
__global__ __launch_bounds__(256) void dispatch_kernel(
    const int* __restrict__ tidx, int* __restrict__ counts,
    int* __restrict__ perm)
{
  int t = blockIdx.x * 256 + threadIdx.x;
  int lane = threadIdx.x & 63;
  #pragma unroll
  for (int k = 0; k < 2; ++k) {
    int e = tidx[2 * t + k];
    #pragma unroll
    for (int ex = 0; ex < NEXP; ++ex) {
      unsigned long long m = __ballot(e == ex);
      if (m) {                                 // wave-uniform
        int leader = __ffsll((unsigned long long)m) - 1;
        int base = 0;
        if (lane == leader) base = atomicAdd(&counts[ex], __popcll(m));
        base = __shfl(base, leader);
        if (e == ex) {
          int pos = base + __popcll(m & ((1ULL << lane) - 1ULL));
          perm[ex * T_TOK + pos] = 2 * t + k;
        }
      }
    }
  }
}

extern "C" void kernel_launch(void* const* d_in, const int* in_sizes, int n_in,
                              void* d_out, int out_size, void* d_ws, size_t ws_size,
                              hipStream_t stream)
{
  const float* x   = (const float*)d_in[0];
  // d_in[1] = task_ids (unused by reference)
  const float* gw1 = (const float*)d_in[2];
  const float* gb1 = (const float*)d_in[3];
  const float* gw2 = (const float*)d_in[4];
  const float* gb2 = (const float*)d_in[5];
  const float* We1 = (const float*)d_in[6];
  const float* be1 = (const float*)d_in[7];
  const float* We2 = (const float*)d_in[8];
  const float* be2 = (const float*)d_in[9];
  const float* Ws1 = (const float*)d_in[10];
  const float* bs1 = (const float*)d_in[11];
  const float* Ws2 = (const float*)d_in[12];
  const float* bs2 = (const float*)d_in[13];
  float* out = (float*)d_out;

  // ---- workspace layout (176.3 MiB, lifetime-overlapped) ----
  char* ws = (char*)d_ws;
  bf16*  xb     = (bf16*)(ws + 0);              // 16 MiB [T,D] hi
  bf16*  We1t   = (bf16*)(ws + 16777216);       // 32 MiB [E,H,D]
  bf16*  Rout   = (bf16*)(ws + 16777216);       // 32 MiB [2T,D] (reuses We1t)
  bf16*  We2t   = (bf16*)(ws + 50331648);       // 32 MiB [E,D,H]
  bf16*  Ws1t   = (bf16*)(ws + 83886080);       //  4 MiB [H,D]
  bf16*  Ws2t   = (bf16*)(ws + 88080384);       //  4 MiB [D,H]
  int*   counts = (int*)(ws + 92274688);        // 1 KiB pad
  float* wslot  = (float*)(ws + 92275712);      // 64 KiB [2T]
  int*   perm   = (int*)(ws + 92341248);        // 256 KiB [E,T]
  bf16*  xl     = (bf16*)(ws + 92603392);       // 16 MiB [T,D] lo
  bf16*  gw1h   = (bf16*)(ws + 109380608);      //  4 MiB [H,D] hi
  bf16*  gw1l   = (bf16*)(ws + 113574912);      //  4 MiB [H,D] lo
  int*   tidx   = (int*)(ws + 113574912);       // 64 KiB [2T] (reuses gw1l after gate GEMM)
  float* G1     = (float*)(ws + 117769216);     // 64 MiB [T,H] fp32
  bf16*  Hrt    = (bf16*)(ws + 117769216);      // 64 MiB [2T,H] (reuses G1)
  bf16*  S1     = (bf16*)(ws + 117769216);      // 32 MiB [T,H]  (reuses Hrt)

  hipMemsetAsync(counts, 0, NEXP * sizeof(int), stream);

  dim3 blk(256);
  // x cast (hi+lo)
  cast_split_x<<<dim3((T_TOK * DDIM) / 1024), blk, 0, stream>>>(x, xb, xl);
  // weight cast+transpose ([K,N] fp32 -> [N,K] bf16)
  transpose_cast<true ><<<dim3(HDIM/32, DDIM/32, 1), blk, 0, stream>>>(gw1, gw1h, gw1l, DDIM, HDIM);
  transpose_cast<false><<<dim3(HDIM/32, DDIM/32, 1), blk, 0, stream>>>(Ws1, Ws1t, nullptr, DDIM, HDIM);
  transpose_cast<false><<<dim3(DDIM/32, HDIM/32, 1), blk, 0, stream>>>(Ws2, Ws2t, nullptr, HDIM, DDIM);
  transpose_cast<false><<<dim3(HDIM/32, DDIM/32, NEXP), blk, 0, stream>>>(We1, We1t, nullptr, DDIM, HDIM);
  transpose_cast<false><<<dim3(DDIM/32, HDIM/32, NEXP), blk, 0, stream>>>(We2, We2t, nullptr, HDIM, DDIM);

  // gate GEMM1 (split-bf16, fused 3-term, fp32 out): G1 = gelu_erf(x @ gw1 + gb1)
  gemm_bt<1, float, 0, false, true, false><<<dim3(HDIM/128, T_TOK/128, 1), blk, 0, stream>>>(
      xb, gw1h, xl, gw1l, gb1, G1, T_TOK, HDIM, DDIM, DDIM, 0, 0,
      nullptr, nullptr, nullptr, nullptr);
  // gating: logits + top-2 + softmax, then ballot-aggregated dispatch
  logits_kernel<<<dim3(T_TOK / 4), blk, 0, stream>>>(G1, gw2, gb2, tidx, wslot);
  dispatch_kernel<<<dim3(T_TOK / 256), blk, 0, stream>>>(tidx, counts, perm);
  // routed experts (gathered) -- before shared so shared GEMM2 can fuse combine
  gemm_bt<2, bf16, 1, false, false, false><<<dim3(HDIM/128, T_TOK/128, NEXP), blk, 0, stream>>>(
      xb, We1t, nullptr, nullptr, be1, Hrt, T_TOK, HDIM, DDIM, DDIM,
      (long)HDIM * DDIM, HDIM, perm, counts, nullptr, nullptr);
  gemm_bt<0, bf16, 2, true, false, false><<<dim3(DDIM/128, T_TOK/128, NEXP), blk, 0, stream>>>(
      Hrt, We2t, nullptr, nullptr, be2, Rout, T_TOK, DDIM, HDIM, HDIM,
      (long)DDIM * HDIM, DDIM, perm, counts, wslot, nullptr);
  // shared expert; GEMM2 epilogue fuses the routed combine -> final out
  gemm_bt<2, bf16, 0, false, false, false><<<dim3(HDIM/128, T_TOK/128, 1), blk, 0, stream>>>(
      xb, Ws1t, nullptr, nullptr, bs1, S1, T_TOK, HDIM, DDIM, DDIM, 0, 0,
      nullptr, nullptr, nullptr, nullptr);
  gemm_bt<0, float, 0, false, false, true><<<dim3(DDIM/128, T_TOK/128, 1), blk, 0, stream>>>(
      S1, Ws2t, nullptr, nullptr, bs2, out, T_TOK, DDIM, HDIM, HDIM, 0, 0,
      nullptr, nullptr, nullptr, Rout);
}